// Round 2
// baseline (218.473 us; speedup 1.0000x reference)
//
#include <hip/hip_runtime.h>
#include <math.h>

#define N_NODES 50000
#define IN_CH 256
#define N_REL 5
#define N_EDGES 800000
#define N_E4 200000        // N_EDGES/4
#define N_GLOB 20000       // LAST_GLOBALS - LAST_SENSES
#define N_SENSE 25000
#define N_OUT 45000
#define MAX_MATCH 256      // E[matches]=16; 256 is astronomically safe
#define N_QUAD 11250       // N_OUT/4
#define Q_GLOB 5000        // N_GLOB/4 — segment boundary is quad-aligned

#define G2 1024            // k2 grid = 4*MAX_MATCH units
#define G3 2048            // k3 grid: 8 blk/CU * 4 waves = 32 waves/CU (BW-saturating)

// ---------------- workspace layout (float offsets from base) ----------------
// W       : [0, 327680)          5*256*256
// sums    : [327680, 328960)     5*256 atomic accumulators  (memset 0)
// rootacc : [328960, 329216)     256 atomic accumulators    (memset 0)
// ip      : ints at 329216       [0]=cnt [1..5]=per-rel cnt [6]=k2ctr [7]=k3ctr
//                                [8..264)=src [264..520)=type   (first 8 memset 0)
// x1      : [329760, 330016)
// stats   : [330016, 330018)     {zg, zs}
// pm/ps   : [330048, +4*G3)      per-block online-softmax partials
#define WS_SUMS 327680
#define WS_ROOTACC 328960
#define WS_IP 329216
#define WS_X1 329760
#define WS_STATS 330016
#define WS_PM 330048

__device__ __forceinline__ float aload(const float* p) {
    return __hip_atomic_load(p, __ATOMIC_RELAXED, __HIP_MEMORY_SCOPE_AGENT);
}

// online log-sum-exp merge: (m,s) <- (m,s) ⊕ (m2,s2)
__device__ __forceinline__ void omerge(float& m, float& s, float m2, float s2) {
    float M = fmaxf(m, m2);
    if (M == -INFINITY) return;          // both neutral: avoid inf-inf = NaN
    s = s * expf(m - M) + s2 * expf(m2 - M);
    m = M;
}

__device__ __forceinline__ void rec(const int* __restrict__ ei,
                                    const int* __restrict__ et,
                                    int* __restrict__ ip, int e) {
    int t = et[e];
    int p = atomicAdd(&ip[0], 1);
    if (p < MAX_MATCH) {
        ip[8 + p] = ei[e];               // src
        ip[8 + MAX_MATCH + p] = t;       // type
    }
    atomicAdd(&ip[1 + t], 1);
}

// ---------- K1: W = comp x basis | edge scan | root GEMV (all independent) ----------
// blocks: [0,1280) W-units, [1280,2062) scan-units, [2062,2066) root K-split
__global__ __launch_bounds__(256) void k1(const float* __restrict__ x,
                                          const int* __restrict__ ei,
                                          const int* __restrict__ et,
                                          const float* __restrict__ comp,
                                          const float* __restrict__ basis,
                                          const float* __restrict__ root,
                                          float* __restrict__ base) {
    float* W = base;
    float* rootacc = base + WS_ROOTACC;
    int* ip = (int*)(base + WS_IP);
    int bid = blockIdx.x, tid = threadIdx.x;
    if (bid < 1280) {
        int idx = bid * 256 + tid;             // < 327680
        int r = idx >> 16, df = idx & 65535;
        float acc = 0.f;
#pragma unroll
        for (int b = 0; b < N_REL; ++b)
            acc += comp[r * N_REL + b] * basis[b * (IN_CH * IN_CH) + df];
        W[idx] = acc;
    } else if (bid < 2062) {
        int e4 = (bid - 1280) * 256 + tid;
        if (e4 < N_E4) {
            int4 d = ((const int4*)(ei + N_EDGES))[e4];
            int e = e4 * 4;
            if (d.x == 0) rec(ei, et, ip, e);
            if (d.y == 0) rec(ei, et, ip, e + 1);
            if (d.z == 0) rec(ei, et, ip, e + 2);
            if (d.w == 0) rec(ei, et, ip, e + 3);
        }
    } else {
        int c = bid - 2062;
        const float* xp = x + c * 64;                   // uniform broadcast reads
        const float* rp = root + c * 64 * IN_CH + tid;  // coalesced rows
        float acc = 0.f;
#pragma unroll 8
        for (int d = 0; d < 64; ++d) acc += xp[d] * rp[d * IN_CH];
        atomicAdd(&rootacc[tid], acc);
    }
}

// ---------- K2: sums[r] += x[src]@W[r]; last-arriving block computes x1 ----------
__global__ __launch_bounds__(256) void k2(const float* __restrict__ x,
                                          const float* __restrict__ bias,
                                          float* __restrict__ base) {
    float* W = base;
    float* sums = base + WS_SUMS;
    float* rootacc = base + WS_ROOTACC;
    int* ip = (int*)(base + WS_IP);
    float* x1 = base + WS_X1;
    int tid = threadIdx.x, bid = blockIdx.x;

    int m = ip[0]; if (m > MAX_MATCH) m = MAX_MATCH;   // from K1 (kernel boundary)
    if (bid < 4 * m) {
        int j = bid >> 2, c = bid & 3;
        int s = ip[8 + j];
        int r = ip[8 + MAX_MATCH + j];
        const float* xp = x + (size_t)s * IN_CH + c * 64;   // uniform broadcast
        const float* wp = W + r * (IN_CH * IN_CH) + c * 64 * IN_CH + tid;
        float acc = 0.f;
#pragma unroll 8
        for (int d = 0; d < 64; ++d) acc += xp[d] * wp[d * IN_CH];
        atomicAdd(&sums[r * IN_CH + tid], acc);
    }
    // deadlock-free last-block pattern (no spinning anywhere)
    __shared__ int slast;
    __syncthreads();                       // all block's atomics issued & drained
    if (tid == 0) {
        __threadfence();                   // release
        int prev = atomicAdd(&ip[6], 1);
        slast = (prev == G2 - 1) ? 1 : 0;
    }
    __syncthreads();
    if (!slast) return;
    __threadfence();                       // acquire
    float a = bias[tid] + rootacc[tid];    // rootacc from K1: plain load OK
#pragma unroll
    for (int r = 0; r < N_REL; ++r)
        a += aload(&sums[r * IN_CH + tid]) / fmaxf((float)ip[1 + r], 1.f);
    x1[tid] = fmaxf(a, 0.f);
}

// ---------- K3: logits + per-block softmax partials; last block reduces -> stats ----------
__global__ __launch_bounds__(256) void k3(const float* __restrict__ Wg,
                                          const float* __restrict__ bg,
                                          const float* __restrict__ Ws,
                                          const float* __restrict__ bs,
                                          float* __restrict__ out,
                                          float* __restrict__ base) {
    __shared__ __align__(16) float sx[IN_CH];
    __shared__ float rbuf[4][4];
    __shared__ int slast;
    __shared__ float rm[256], rs[256];
    float* x1 = base + WS_X1;
    int* ip = (int*)(base + WS_IP);
    float* stats = base + WS_STATS;
    float* pm_g = base + WS_PM;
    float* ps_g = pm_g + G3;
    float* pm_s = ps_g + G3;
    float* ps_s = pm_s + G3;

    int tid = threadIdx.x, bid = blockIdx.x;
    sx[tid] = x1[tid];                     // from K2 (kernel boundary)
    __syncthreads();

    const int lane = tid & 63, w = tid >> 6;
    float4 xv = ((const float4*)sx)[lane];
    float mg = -INFINITY, sg = 0.f, ms = -INFINITY, ss = 0.f;

    for (int q = bid * 4 + w; q < N_QUAD; q += G3 * 4) {   // one wave: 4 rows
        const float* mat; const float* bv; int rl;
        if (q < Q_GLOB) { mat = Wg; bv = bg; rl = q * 4; }
        else            { mat = Ws; bv = bs; rl = q * 4 - N_GLOB; }
        const float4* p = (const float4*)(mat + (size_t)rl * IN_CH);
        float4 a0 = p[lane], a1 = p[64 + lane], a2 = p[128 + lane], a3 = p[192 + lane];
        float d0 = a0.x * xv.x + a0.y * xv.y + a0.z * xv.z + a0.w * xv.w;
        float d1 = a1.x * xv.x + a1.y * xv.y + a1.z * xv.z + a1.w * xv.w;
        float d2 = a2.x * xv.x + a2.y * xv.y + a2.z * xv.z + a2.w * xv.w;
        float d3 = a3.x * xv.x + a3.y * xv.y + a3.z * xv.z + a3.w * xv.w;
#pragma unroll
        for (int off = 32; off; off >>= 1) {
            d0 += __shfl_xor(d0, off); d1 += __shfl_xor(d1, off);
            d2 += __shfl_xor(d2, off); d3 += __shfl_xor(d3, off);
        }
        float4 bq = *(const float4*)(bv + rl);
        float l0 = d0 + bq.x, l1 = d1 + bq.y, l2 = d2 + bq.z, l3 = d3 + bq.w;
        if (lane == 0) ((float4*)out)[q] = make_float4(l0, l1, l2, l3);
        float lm = fmaxf(fmaxf(l0, l1), fmaxf(l2, l3));
        float le = expf(l0 - lm) + expf(l1 - lm) + expf(l2 - lm) + expf(l3 - lm);
        if (q < Q_GLOB) omerge(mg, sg, lm, le);
        else            omerge(ms, ss, lm, le);
    }
    if (lane == 0) { rbuf[w][0] = mg; rbuf[w][1] = sg; rbuf[w][2] = ms; rbuf[w][3] = ss; }
    __syncthreads();
    if (tid == 0) {
        float M0 = rbuf[0][0], S0 = rbuf[0][1], M1 = rbuf[0][2], S1 = rbuf[0][3];
#pragma unroll
        for (int i = 1; i < 4; ++i) {
            omerge(M0, S0, rbuf[i][0], rbuf[i][1]);
            omerge(M1, S1, rbuf[i][2], rbuf[i][3]);
        }
        pm_g[bid] = M0; ps_g[bid] = S0; pm_s[bid] = M1; ps_s[bid] = S1;
        __threadfence();                   // release partials
        int prev = atomicAdd(&ip[7], 1);
        slast = (prev == G3 - 1) ? 1 : 0;
    }
    __syncthreads();
    if (!slast) return;
    __threadfence();                       // acquire

    float M = -INFINITY, S = 0.f;
    for (int i = tid; i < G3; i += 256) omerge(M, S, aload(&pm_g[i]), aload(&ps_g[i]));
    rm[tid] = M; rs[tid] = S; __syncthreads();
    for (int h = 128; h; h >>= 1) {
        if (tid < h) omerge(rm[tid], rs[tid], rm[tid + h], rs[tid + h]);
        __syncthreads();
    }
    if (tid == 0) stats[0] = rm[0] + logf(rs[0]);
    __syncthreads();
    M = -INFINITY; S = 0.f;
    for (int i = tid; i < G3; i += 256) omerge(M, S, aload(&pm_s[i]), aload(&ps_s[i]));
    rm[tid] = M; rs[tid] = S; __syncthreads();
    for (int h = 128; h; h >>= 1) {
        if (tid < h) omerge(rm[tid], rs[tid], rm[tid + h], rs[tid + h]);
        __syncthreads();
    }
    if (tid == 0) stats[1] = rm[0] + logf(rs[0]);
}

// ---------- K4: out -= logZ[segment] ----------
__global__ __launch_bounds__(256) void k4(float* __restrict__ out,
                                          const float* __restrict__ base) {
    const float* stats = base + WS_STATS;
    int i = blockIdx.x * 256 + threadIdx.x;
    if (i >= N_OUT) return;
    out[i] -= (i < N_GLOB) ? stats[0] : stats[1];
}

extern "C" void kernel_launch(void* const* d_in, const int* in_sizes, int n_in,
                              void* d_out, int out_size, void* d_ws, size_t ws_size,
                              hipStream_t stream) {
    const float* x     = (const float*)d_in[0];
    const int*   ei    = (const int*)  d_in[1];
    const int*   et    = (const int*)  d_in[2];
    const float* comp  = (const float*)d_in[3];
    const float* basis = (const float*)d_in[4];
    const float* root  = (const float*)d_in[5];
    const float* bias  = (const float*)d_in[6];
    const float* Wg    = (const float*)d_in[7];
    const float* bg    = (const float*)d_in[8];
    const float* Wsn   = (const float*)d_in[9];
    const float* bs    = (const float*)d_in[10];
    float* out  = (float*)d_out;
    float* base = (float*)d_ws;

    // zero atomic landing zones: sums(1280f)+rootacc(256f)+ip[0..7] = 6176 B
    hipMemsetAsync(base + WS_SUMS, 0, 6176, stream);

    k1<<<2066, 256, 0, stream>>>(x, ei, et, comp, basis, root, base);
    k2<<<G2,   256, 0, stream>>>(x, bias, base);
    k3<<<G3,   256, 0, stream>>>(Wg, bg, Wsn, bs, out, base);
    k4<<<(N_OUT + 255) / 256, 256, 0, stream>>>(out, base);
}

// Round 3
// 146.567 us; speedup vs baseline: 1.4906x; 1.4906x over previous
//
#include <hip/hip_runtime.h>
#include <math.h>

#define N_NODES 50000
#define IN_CH 256
#define N_REL 5
#define N_EDGES 800000
#define N_E4 200000        // N_EDGES/4
#define N_GLOB 20000       // LAST_GLOBALS - LAST_SENSES
#define N_SENSE 25000
#define N_OUT 45000
#define MAX_MATCH 256      // E[matches]=16; 256 is astronomically safe
#define N_QUAD 11250       // N_OUT/4
#define Q_GLOB 5000        // N_GLOB/4 — segment boundary is quad-aligned

#define G2 1024            // k2 grid = 4*MAX_MATCH units (most exit immediately)
#define G3 2048            // k3 grid: 8 blk/CU — BW-saturating

// ---------------- workspace layout (float offsets from base) ----------------
// W       : [0, 327680)          5*256*256
// sums    : [327680, 328960)     5*256 atomic accumulators  (memset 0)
// rootacc : [328960, 329216)     256 atomic accumulators    (memset 0)
// ip      : ints at 329216       [0]=cnt [1..5]=per-rel cnt (first 8 memset 0)
//                                [8..264)=src [264..520)=type
// pm/ps   : [329744, +4*G3)      per-block online-softmax partials
#define WS_SUMS 327680
#define WS_ROOTACC 328960
#define WS_IP 329216
#define WS_PM 329744

// online log-sum-exp merge: (m,s) <- (m,s) ⊕ (m2,s2)
__device__ __forceinline__ void omerge(float& m, float& s, float m2, float s2) {
    float M = fmaxf(m, m2);
    if (M == -INFINITY) return;          // both neutral: avoid inf-inf = NaN
    s = s * expf(m - M) + s2 * expf(m2 - M);
    m = M;
}

__device__ __forceinline__ void rec(const int* __restrict__ ei,
                                    const int* __restrict__ et,
                                    int* __restrict__ ip, int e) {
    int t = et[e];
    int p = atomicAdd(&ip[0], 1);
    if (p < MAX_MATCH) {
        ip[8 + p] = ei[e];               // src
        ip[8 + MAX_MATCH + p] = t;       // type
    }
    atomicAdd(&ip[1 + t], 1);
}

// ---------- K1: W = comp x basis | edge scan | root GEMV (all independent) ----------
// blocks: [0,1280) W-units, [1280,2062) scan-units, [2062,2066) root K-split
__global__ __launch_bounds__(256) void k1(const float* __restrict__ x,
                                          const int* __restrict__ ei,
                                          const int* __restrict__ et,
                                          const float* __restrict__ comp,
                                          const float* __restrict__ basis,
                                          const float* __restrict__ root,
                                          float* __restrict__ base) {
    float* W = base;
    float* rootacc = base + WS_ROOTACC;
    int* ip = (int*)(base + WS_IP);
    int bid = blockIdx.x, tid = threadIdx.x;
    if (bid < 1280) {
        int idx = bid * 256 + tid;             // < 327680
        int r = idx >> 16, df = idx & 65535;
        float acc = 0.f;
#pragma unroll
        for (int b = 0; b < N_REL; ++b)
            acc += comp[r * N_REL + b] * basis[b * (IN_CH * IN_CH) + df];
        W[idx] = acc;
    } else if (bid < 2062) {
        int e4 = (bid - 1280) * 256 + tid;
        if (e4 < N_E4) {
            int4 d = ((const int4*)(ei + N_EDGES))[e4];
            int e = e4 * 4;
            if (d.x == 0) rec(ei, et, ip, e);
            if (d.y == 0) rec(ei, et, ip, e + 1);
            if (d.z == 0) rec(ei, et, ip, e + 2);
            if (d.w == 0) rec(ei, et, ip, e + 3);
        }
    } else {
        int c = bid - 2062;
        const float* xp = x + c * 64;                   // uniform broadcast reads
        const float* rp = root + c * 64 * IN_CH + tid;  // coalesced rows
        float acc = 0.f;
#pragma unroll 8
        for (int d = 0; d < 64; ++d) acc += xp[d] * rp[d * IN_CH];
        atomicAdd(&rootacc[tid], acc);
    }
}

// ---------- K2: sums[r] += x[src]@W[r]  (pure; no fences, no handoff) ----------
__global__ __launch_bounds__(256) void k2(const float* __restrict__ x,
                                          float* __restrict__ base) {
    const float* W = base;
    float* sums = base + WS_SUMS;
    const int* ip = (const int*)(base + WS_IP);
    int tid = threadIdx.x, bid = blockIdx.x;

    int m = ip[0]; if (m > MAX_MATCH) m = MAX_MATCH;   // from K1 (kernel boundary)
    if (bid >= 4 * m) return;
    int j = bid >> 2, c = bid & 3;
    int s = ip[8 + j];
    int r = ip[8 + MAX_MATCH + j];
    const float* xp = x + (size_t)s * IN_CH + c * 64;   // uniform broadcast
    const float* wp = W + r * (IN_CH * IN_CH) + c * 64 * IN_CH + tid;
    float acc = 0.f;
#pragma unroll 8
    for (int d = 0; d < 64; ++d) acc += xp[d] * wp[d * IN_CH];
    atomicAdd(&sums[r * IN_CH + tid], acc);
}

// ---------- K3: per-lane x1 (redundant, no LDS/barrier) + logits + block partials ----------
__global__ __launch_bounds__(256) void k3(const float* __restrict__ bias,
                                          const float* __restrict__ Wg,
                                          const float* __restrict__ bg,
                                          const float* __restrict__ Ws,
                                          const float* __restrict__ bs,
                                          float* __restrict__ out,
                                          float* __restrict__ base) {
    __shared__ float rbuf[4][4];
    const float* sums = base + WS_SUMS;
    const float* rootacc = base + WS_ROOTACC;
    const int* ip = (const int*)(base + WS_IP);
    float* pm_g = base + WS_PM;
    float* ps_g = pm_g + G3;
    float* pm_s = ps_g + G3;
    float* ps_s = pm_s + G3;

    int tid = threadIdx.x, bid = blockIdx.x;
    const int lane = tid & 63, w = tid >> 6;

    // x1 slice for this lane: elements 4*lane .. 4*lane+3 (broadcast L2 reads)
    float4 xv;
    {
        float4 bq = ((const float4*)bias)[lane];
        float4 ra = ((const float4*)rootacc)[lane];
        xv.x = bq.x + ra.x; xv.y = bq.y + ra.y;
        xv.z = bq.z + ra.z; xv.w = bq.w + ra.w;
#pragma unroll
        for (int r = 0; r < N_REL; ++r) {
            float4 sv = ((const float4*)(sums + r * IN_CH))[lane];
            float inv = 1.f / fmaxf((float)ip[1 + r], 1.f);
            xv.x += sv.x * inv; xv.y += sv.y * inv;
            xv.z += sv.z * inv; xv.w += sv.w * inv;
        }
        xv.x = fmaxf(xv.x, 0.f); xv.y = fmaxf(xv.y, 0.f);
        xv.z = fmaxf(xv.z, 0.f); xv.w = fmaxf(xv.w, 0.f);
    }

    float mg = -INFINITY, sg = 0.f, ms = -INFINITY, ss = 0.f;

    for (int q = bid * 4 + w; q < N_QUAD; q += G3 * 4) {   // one wave: 4 rows
        const float* mat; const float* bv; int rl;
        if (q < Q_GLOB) { mat = Wg; bv = bg; rl = q * 4; }
        else            { mat = Ws; bv = bs; rl = q * 4 - N_GLOB; }
        const float4* p = (const float4*)(mat + (size_t)rl * IN_CH);
        float4 a0 = p[lane], a1 = p[64 + lane], a2 = p[128 + lane], a3 = p[192 + lane];
        float d0 = a0.x * xv.x + a0.y * xv.y + a0.z * xv.z + a0.w * xv.w;
        float d1 = a1.x * xv.x + a1.y * xv.y + a1.z * xv.z + a1.w * xv.w;
        float d2 = a2.x * xv.x + a2.y * xv.y + a2.z * xv.z + a2.w * xv.w;
        float d3 = a3.x * xv.x + a3.y * xv.y + a3.z * xv.z + a3.w * xv.w;
#pragma unroll
        for (int off = 32; off; off >>= 1) {
            d0 += __shfl_xor(d0, off); d1 += __shfl_xor(d1, off);
            d2 += __shfl_xor(d2, off); d3 += __shfl_xor(d3, off);
        }
        float4 bq = *(const float4*)(bv + rl);
        float l0 = d0 + bq.x, l1 = d1 + bq.y, l2 = d2 + bq.z, l3 = d3 + bq.w;
        if (lane == 0) ((float4*)out)[q] = make_float4(l0, l1, l2, l3);
        float lm = fmaxf(fmaxf(l0, l1), fmaxf(l2, l3));
        float le = expf(l0 - lm) + expf(l1 - lm) + expf(l2 - lm) + expf(l3 - lm);
        if (q < Q_GLOB) omerge(mg, sg, lm, le);
        else            omerge(ms, ss, lm, le);
    }
    if (lane == 0) { rbuf[w][0] = mg; rbuf[w][1] = sg; rbuf[w][2] = ms; rbuf[w][3] = ss; }
    __syncthreads();
    if (tid == 0) {
        float M0 = rbuf[0][0], S0 = rbuf[0][1], M1 = rbuf[0][2], S1 = rbuf[0][3];
#pragma unroll
        for (int i = 1; i < 4; ++i) {
            omerge(M0, S0, rbuf[i][0], rbuf[i][1]);
            omerge(M1, S1, rbuf[i][2], rbuf[i][3]);
        }
        pm_g[bid] = M0; ps_g[bid] = S0; pm_s[bid] = M1; ps_s[bid] = S1;
    }
}

// ---------- K4: redundant partial-reduce per block, then out -= logZ[segment] ----------
__global__ __launch_bounds__(256) void k4(float* __restrict__ out,
                                          const float* __restrict__ base) {
    __shared__ float rm[256], rs[256];
    const float* pm_g = base + WS_PM;
    const float* ps_g = pm_g + G3;
    const float* pm_s = ps_g + G3;
    const float* ps_s = pm_s + G3;
    int tid = threadIdx.x;
    int i = blockIdx.x * 256 + tid;
    float v = (i < N_OUT) ? out[i] : 0.f;   // issue early, overlaps reduction

    float M = -INFINITY, S = 0.f;
#pragma unroll
    for (int j = 0; j < G3 / 256; ++j) omerge(M, S, pm_g[tid + j * 256], ps_g[tid + j * 256]);
    rm[tid] = M; rs[tid] = S; __syncthreads();
    for (int h = 128; h; h >>= 1) {
        if (tid < h) omerge(rm[tid], rs[tid], rm[tid + h], rs[tid + h]);
        __syncthreads();
    }
    float zg = rm[0] + logf(rs[0]);
    __syncthreads();

    M = -INFINITY; S = 0.f;
#pragma unroll
    for (int j = 0; j < G3 / 256; ++j) omerge(M, S, pm_s[tid + j * 256], ps_s[tid + j * 256]);
    rm[tid] = M; rs[tid] = S; __syncthreads();
    for (int h = 128; h; h >>= 1) {
        if (tid < h) omerge(rm[tid], rs[tid], rm[tid + h], rs[tid + h]);
        __syncthreads();
    }
    float zs = rm[0] + logf(rs[0]);

    if (i < N_OUT) out[i] = v - ((i < N_GLOB) ? zg : zs);
}

extern "C" void kernel_launch(void* const* d_in, const int* in_sizes, int n_in,
                              void* d_out, int out_size, void* d_ws, size_t ws_size,
                              hipStream_t stream) {
    const float* x     = (const float*)d_in[0];
    const int*   ei    = (const int*)  d_in[1];
    const int*   et    = (const int*)  d_in[2];
    const float* comp  = (const float*)d_in[3];
    const float* basis = (const float*)d_in[4];
    const float* root  = (const float*)d_in[5];
    const float* bias  = (const float*)d_in[6];
    const float* Wg    = (const float*)d_in[7];
    const float* bg    = (const float*)d_in[8];
    const float* Wsn   = (const float*)d_in[9];
    const float* bs    = (const float*)d_in[10];
    float* out  = (float*)d_out;
    float* base = (float*)d_ws;

    // zero atomic landing zones: sums(1280f)+rootacc(256f)+ip[0..7] = 6176 B
    hipMemsetAsync(base + WS_SUMS, 0, 6176, stream);

    k1<<<2066, 256, 0, stream>>>(x, ei, et, comp, basis, root, base);
    k2<<<G2,   256, 0, stream>>>(x, base);
    k3<<<G3,   256, 0, stream>>>(bias, Wg, bg, Wsn, bs, out, base);
    k4<<<(N_OUT + 255) / 256, 256, 0, stream>>>(out, base);
}